// Round 10
// baseline (66.566 us; speedup 1.0000x reference)
//
#include <hip/hip_runtime.h>
#include <math.h>

#define ROWS 512
#define DIM 2048
#define MS 51            // MAX_SHIFT
#define NWIN 103         // 2*MS+1
#define KMIN 32          // HIGHPASS bins
#define NMASK 993        // 1025-32

// One block (512 threads, 8 waves) per row. 8 intervals / 7 barriers.
//  I0: strided load + stats partials + head/tail stage + FFT1 r4 s=1 (regs)
//  I1: FFT1 r8 s=4 (t<256) || stats reduce (w4) || prefix scans (w5,w6)
//  I2: FFT1 r8 s=32 (t<256) || wrap edge-sums (t>=256)
//  I3: FFT1 r8 s=256 tw-free -> full X in B2
//  I4: Q-build + FFT2 r4 s=1 (t<256) || e/g + scan shfl (t>=256)
//  I5: FFT2 r8 s=4 (t<128) || scan writeback (t>=256)
//  I6: FFT2 r8 s=32 (t<128) || w4: searchsorted+summ+chisq -> sc[7]
//  I7: w0: fused final r4 + Pearson (2 lags/lane) + in-wave max -> out
__global__ __launch_bounds__(512) void fused_mfl_kernel(
    const float* __restrict__ xhat, const float* __restrict__ x,
    float* __restrict__ out)
{
    const int r = blockIdx.x;
    const int t = threadIdx.x;
    const int lane = t & 63;
    const int wave = t >> 6;          // 0..7

    __shared__ float smem[13056];     // 51 KB arena
    float2* A2  = (float2*)smem;                 // 2048 cplx [0,4096)
    float2* B2  = (float2*)(smem + 4096);        // 2048 cplx [4096,8192)
    float2* TW  = (float2*)(smem + 8192);        // 512 cplx  [8192,9216)
    float2* Qlo = (float2*)smem;                 // 1024 cplx [0,2048)
    float2* Qhi = (float2*)smem + 1024;          // 1024 cplx [2048,4096)
    float* siA  = smem + 4096;                   // 1024 (B2 region, post-I4)
    float* siBr = smem + 5120;                   // 1024
    float* red6 = smem + 9216;                   // 3072 (dead after I1)
    float* ah   = smem + 12288;                  // 51 raw a head
    float* xhd  = smem + 12339;                  // 51 raw x head
    float* at_  = smem + 12390;                  // 51 raw a tail
    float* xt_  = smem + 12441;                  // 51 raw x tail
    float* Ah   = smem + 12492;                  // 52 prefix sums
    float* Aqh  = smem + 12544;
    float* Xh   = smem + 12596;
    float* At   = smem + 12648;
    float* Aqt  = smem + 12700;
    float* Xt   = smem + 12752;
    float* accv = smem + 12804;                  // 103 wrap edge-sums

    __shared__ float sc[8];
    __shared__ float wsA[4], wsB[4];

    const float* xhp = xhat + (size_t)r * DIM;
    const float* xrp = x    + (size_t)r * DIM;
    // strided load: thread t holds samples {t, t+512, t+1024, t+1536}
    float av[4] = {xhp[t], xhp[t+512], xhp[t+1024], xhp[t+1536]};
    float bv[4] = {xrp[t], xrp[t+512], xrp[t+1024], xrp[t+1536]};

    // twiddle: TW[u] = exp(-i*pi*u/1024); this thread's s=1 twiddle = TW[t]
    float swv, cwv;
    __sincosf((float)t * (-3.14159265358979323846f / 1024.0f), &swv, &cwv);
    TW[t] = make_float2(cwv, swv);

    // ---- I0: stats partials + head/tail + FFT1 r4 s=1 from registers -------
    {
        float mn4 = fminf(fminf(av[0],av[1]), fminf(av[2],av[3]));
        float mx4 = fmaxf(fmaxf(av[0],av[1]), fmaxf(av[2],av[3]));
        float sa = (av[0]+av[1])+(av[2]+av[3]);
        float qa = (av[0]*av[0]+av[1]*av[1])+(av[2]*av[2]+av[3]*av[3]);
        float sx = (bv[0]+bv[1])+(bv[2]+bv[3]);
        float qx = (bv[0]*bv[0]+bv[1]*bv[1])+(bv[2]*bv[2]+bv[3]*bv[3]);
        red6[t] = mn4; red6[512+t] = mx4; red6[1024+t] = sa;
        red6[1536+t] = qa; red6[2048+t] = sx; red6[2560+t] = qx;
    }
    if (t < MS)   { ah[t] = av[0];      xhd[t] = bv[0]; }
    if (t >= 461) { at_[t-461] = av[3]; xt_[t-461] = bv[3]; }  // samples 1997..2047
    {
        // radix-4 butterfly, s=1, u=q=t, w1 = (cwv,swv) local -> A2
        float t0r=av[0]+av[2], t0i=bv[0]+bv[2];
        float t1r=av[0]-av[2], t1i=bv[0]-bv[2];
        float t2r=av[1]+av[3], t2i=bv[1]+bv[3];
        float d3r=av[1]-av[3], d3i=bv[1]-bv[3];
        float t3r=d3i, t3i=-d3r;
        float w1r=cwv, w1i=swv;
        float w2r=w1r*w1r-w1i*w1i, w2i=2.f*w1r*w1i;
        float w3r=w2r*w1r-w2i*w1i, w3i=w2r*w1i+w2i*w1r;
        float y0r=t0r+t2r, y0i=t0i+t2i;
        float a1r=t1r+t3r, a1i=t1i+t3i;
        float y1r=a1r*w1r-a1i*w1i, y1i=a1r*w1i+a1i*w1r;
        float a2r=t0r-t2r, a2i=t0i-t2i;
        float y2r=a2r*w2r-a2i*w2i, y2i=a2r*w2i+a2i*w2r;
        float a3r=t1r-t3r, a3i=t1i-t3i;
        float y3r=a3r*w3r-a3i*w3i, y3i=a3r*w3i+a3i*w3r;
        A2[4*t]   = make_float2(y0r,y0i);
        A2[4*t+1] = make_float2(y1r,y1i);
        A2[4*t+2] = make_float2(y2r,y2i);
        A2[4*t+3] = make_float2(y3r,y3i);
    }
    __syncthreads();                                   // B1

    // generic radix-8 Stockham DIF stage; rs = N/8 read stride, tm = TW index
    // multiplier (1 for N=2048, 2 for N=1024). Caller guards thread range.
    auto fft_r8 = [&](const float2* Sp, float2* Dp, const int s,
                      const int rs, const int tm, const bool tw) {
        const int q = t;
        const int u = q & ~(s - 1);
        float2 x0=Sp[q],      x1=Sp[q+rs],   x2=Sp[q+2*rs], x3=Sp[q+3*rs];
        float2 x4=Sp[q+4*rs], x5=Sp[q+5*rs], x6=Sp[q+6*rs], x7=Sp[q+7*rs];
        float e0r=x0.x+x4.x, e0i=x0.y+x4.y;
        float e1r=x0.x-x4.x, e1i=x0.y-x4.y;
        float e2r=x2.x+x6.x, e2i=x2.y+x6.y;
        float e3r=x2.x-x6.x, e3i=x2.y-x6.y;
        float A0r=e0r+e2r, A0i=e0i+e2i;
        float A1r=e1r+e3i, A1i=e1i-e3r;
        float A2r_=e0r-e2r, A2i_=e0i-e2i;
        float A3r=e1r-e3i, A3i=e1i+e3r;
        float o0r=x1.x+x5.x, o0i=x1.y+x5.y;
        float o1r=x1.x-x5.x, o1i=x1.y-x5.y;
        float o2r=x3.x+x7.x, o2i=x3.y+x7.y;
        float o3r=x3.x-x7.x, o3i=x3.y-x7.y;
        float B0r=o0r+o2r, B0i=o0i+o2i;
        float B1r=o1r+o3i, B1i=o1i-o3r;
        float B2r_=o0r-o2r, B2i_=o0i-o2i;
        float B3r=o1r-o3i, B3i=o1i+o3r;
        const float RT = 0.70710678118654752f;
        float C1r = RT*(B1r + B1i), C1i = RT*(B1i - B1r);
        float C2r = B2i_,           C2i = -B2r_;
        float C3r = RT*(B3i - B3r), C3i = -RT*(B3r + B3i);
        float y0r=A0r+B0r,  y0i=A0i+B0i;
        float y1r=A1r+C1r,  y1i=A1i+C1i;
        float y2r=A2r_+C2r, y2i=A2i_+C2i;
        float y3r=A3r+C3r,  y3i=A3i+C3i;
        float y4r=A0r-B0r,  y4i=A0i-B0i;
        float y5r=A1r-C1r,  y5i=A1i-C1i;
        float y6r=A2r_-C2r, y6i=A2i_-C2i;
        float y7r=A3r-C3r,  y7i=A3i-C3i;
        int base = q + 7*u;
        Dp[base] = make_float2(y0r, y0i);
        if (tw) {
            float2 w1 = TW[tm*u];
            auto cm = [](float ar, float ai, float br, float bi, float* rr, float* ri) {
                *rr = ar*br - ai*bi; *ri = ar*bi + ai*br;
            };
            float w2r,w2i,w3r,w3i,w4r,w4i,w5r,w5i,w6r,w6i,w7r,w7i;
            cm(w1.x,w1.y,w1.x,w1.y,&w2r,&w2i);
            cm(w2r,w2i,w1.x,w1.y,&w3r,&w3i);
            cm(w2r,w2i,w2r,w2i,&w4r,&w4i);
            cm(w2r,w2i,w3r,w3i,&w5r,&w5i);
            cm(w3r,w3i,w3r,w3i,&w6r,&w6i);
            cm(w3r,w3i,w4r,w4i,&w7r,&w7i);
            float rr, ri;
            cm(y1r,y1i,w1.x,w1.y,&rr,&ri); Dp[base+s]   = make_float2(rr,ri);
            cm(y2r,y2i,w2r,w2i,&rr,&ri);   Dp[base+2*s] = make_float2(rr,ri);
            cm(y3r,y3i,w3r,w3i,&rr,&ri);   Dp[base+3*s] = make_float2(rr,ri);
            cm(y4r,y4i,w4r,w4i,&rr,&ri);   Dp[base+4*s] = make_float2(rr,ri);
            cm(y5r,y5i,w5r,w5i,&rr,&ri);   Dp[base+5*s] = make_float2(rr,ri);
            cm(y6r,y6i,w6r,w6i,&rr,&ri);   Dp[base+6*s] = make_float2(rr,ri);
            cm(y7r,y7i,w7r,w7i,&rr,&ri);   Dp[base+7*s] = make_float2(rr,ri);
        } else {
            Dp[base+s]   = make_float2(y1r,y1i);
            Dp[base+2*s] = make_float2(y2r,y2i);
            Dp[base+3*s] = make_float2(y3r,y3i);
            Dp[base+4*s] = make_float2(y4r,y4i);
            Dp[base+5*s] = make_float2(y5r,y5i);
            Dp[base+6*s] = make_float2(y6r,y6i);
            Dp[base+7*s] = make_float2(y7r,y7i);
        }
    };

    // ---- I1: FFT1 r8 s=4 (t<256) || stats reduce (w4) || scans (w5,w6) -----
    if (t < 256) {
        fft_r8(A2, B2, 4, 256, 1, true);
    } else if (wave == 4) {
        float4 u, v;
        u=((const float4*)(red6     ))[2*lane]; v=((const float4*)(red6     ))[2*lane+1];
        float pmn=fminf(fminf(fminf(u.x,u.y),fminf(u.z,u.w)),fminf(fminf(v.x,v.y),fminf(v.z,v.w)));
        u=((const float4*)(red6+ 512))[2*lane]; v=((const float4*)(red6+ 512))[2*lane+1];
        float pmx=fmaxf(fmaxf(fmaxf(u.x,u.y),fmaxf(u.z,u.w)),fmaxf(fmaxf(v.x,v.y),fmaxf(v.z,v.w)));
        u=((const float4*)(red6+1024))[2*lane]; v=((const float4*)(red6+1024))[2*lane+1];
        float psa=((u.x+u.y)+(u.z+u.w))+((v.x+v.y)+(v.z+v.w));
        u=((const float4*)(red6+1536))[2*lane]; v=((const float4*)(red6+1536))[2*lane+1];
        float pqa=((u.x+u.y)+(u.z+u.w))+((v.x+v.y)+(v.z+v.w));
        u=((const float4*)(red6+2048))[2*lane]; v=((const float4*)(red6+2048))[2*lane+1];
        float psx=((u.x+u.y)+(u.z+u.w))+((v.x+v.y)+(v.z+v.w));
        u=((const float4*)(red6+2560))[2*lane]; v=((const float4*)(red6+2560))[2*lane+1];
        float pqx=((u.x+u.y)+(u.z+u.w))+((v.x+v.y)+(v.z+v.w));
#pragma unroll
        for (int d = 32; d; d >>= 1) {
            pmn=fminf(pmn,__shfl_down(pmn,d)); pmx=fmaxf(pmx,__shfl_down(pmx,d));
            psa+=__shfl_down(psa,d); pqa+=__shfl_down(pqa,d);
            psx+=__shfl_down(psx,d); pqx+=__shfl_down(pqx,d);
        }
        if (lane == 0) {
            float scl = 2.0f/(pmx - pmn);
            float Cc  = scl*pmn + 1.0f;          // y = scl*a - Cc
            float mean = psx * (1.0f/DIM);
            sc[0]=scl; sc[1]=Cc; sc[2]=mean; sc[3]=psa; sc[4]=pqa;
            sc[5]=pqx - (float)DIM*mean*mean;    // Szz
        }
    } else if (wave == 5) {
        float va=0.f, vq=0.f, vx=0.f;
        if (lane >= 1 && lane <= MS) { float aa=ah[lane-1]; va=aa; vq=aa*aa; vx=xhd[lane-1]; }
#pragma unroll
        for (int d = 1; d < 64; d <<= 1) {
            float ya=__shfl_up(va,d), yq=__shfl_up(vq,d), yx=__shfl_up(vx,d);
            if (lane >= d) { va+=ya; vq+=yq; vx+=yx; }
        }
        if (lane <= MS) { Ah[lane]=va; Aqh[lane]=vq; Xh[lane]=vx; }
    } else if (wave == 6) {
        float va=0.f, vq=0.f, vx=0.f;
        if (lane >= 1 && lane <= MS) { float aa=at_[MS-lane]; va=aa; vq=aa*aa; vx=xt_[MS-lane]; }
#pragma unroll
        for (int d = 1; d < 64; d <<= 1) {
            float ya=__shfl_up(va,d), yq=__shfl_up(vq,d), yx=__shfl_up(vx,d);
            if (lane >= d) { va+=ya; vq+=yq; vx+=yx; }
        }
        if (lane <= MS) { At[lane]=va; Aqt[lane]=vq; Xt[lane]=vx; }
    }
    __syncthreads();                                   // B2

    // ---- I2: FFT1 r8 s=32 (t<256) || wrap edge-sums (t>=256) ---------------
    if (t < 256) {
        fft_r8(B2, A2, 32, 256, 1, true);
    } else {
        int idx = t - 256;
        int c = idx >> 1, k2 = idx & 1;
        if (c < NWIN) {
            const float mean = sc[2];
            int off = c - MS;
            float acc = 0.f;
            if (off > 0) {
                for (int j = k2; j < off; j += 2) acc += ah[j] * (xt_[MS-off+j] - mean);
            } else if (off < 0) {
                int o = -off;
                for (int j = k2; j < o; j += 2) acc += at_[MS-o+j] * (xhd[j] - mean);
            }
            acc += __shfl_down(acc, 1);
            if (k2 == 0) accv[c] = acc;
        }
    }
    __syncthreads();                                   // B3
    if (t < 256) { fft_r8(A2, B2, 256, 256, 1, false); }   // twiddle-free final
    __syncthreads();                                   // B4
    // Full FFT1 result X in B2.

    const float MSC = 0.5f * (1.0f / 2048.0f);

    // scan locals persist across intervals (waves 4-7)
    float se0=0,se1=0,se2=0,se3=0, sg0=0,sg1=0,sg2=0,sg3=0;
    float incE=0, incG=0, totE=0, totG=0;

    // ---- I4: Q-build + FFT2 r4 s=1 (t<256) || e/g + scan shfl (t>=256) -----
    if (t < 256) {
        const int q = t;
        float2 wA = TW[q], wB = TW[q + 256];
        auto mkQ = [&](int k, float2 w, int ni) -> float2 {
            float2 Pa, Pb;
            if (k == 0) {
                float2 Xm = B2[1024];
                Pa = make_float2(0.f, 0.f);
                Pb = make_float2(4.f * Xm.x * Xm.y, 0.f);      // P[1024] (real)
            } else {
                float2 Xk = B2[k], Xn = B2[2048-k];
                float hre = Xk.x + Xn.x, him = Xk.y - Xn.y;
                float sre = Xk.y + Xn.y, sim = Xn.x - Xk.x;
                Pa = make_float2(hre*sre + him*sim, -(him*sre - hre*sim));
                float2 Xm = B2[1024-k], Xp = B2[1024+k];
                float hre2 = Xm.x + Xp.x, him2 = Xm.y - Xp.y;
                float sre2 = Xm.y + Xp.y, sim2 = Xp.x - Xm.x;
                Pb = make_float2(hre2*sre2 + him2*sim2, him2*sre2 - hre2*sim2);
            }
            float D1r = Pa.x + Pb.x, D1i = Pa.y + Pb.y;
            float D2r = Pa.x - Pb.x, D2i = Pa.y - Pb.y;
            float Er = D2r*w.x - D2i*w.y;
            float Ei = D2r*w.y + D2i*w.x;
            if (ni) return make_float2(D1r - Er, D1i - Ei);
            return make_float2(D1r + Ei, D1i - Er);
        };
        float2 x0 = mkQ(q,     wA, 0);
        float2 x1 = mkQ(q+256, wB, 0);
        float2 x2 = mkQ(q+512, wA, 1);
        float2 x3 = mkQ(q+768, wB, 1);
        float t0r=x0.x+x2.x, t0i=x0.y+x2.y;
        float t1r=x0.x-x2.x, t1i=x0.y-x2.y;
        float t2r=x1.x+x3.x, t2i=x1.y+x3.y;
        float d3r=x1.x-x3.x, d3i=x1.y-x3.y;
        float t3r=d3i, t3i=-d3r;
        float2 w1 = TW[2*q];
        float w2r=w1.x*w1.x-w1.y*w1.y, w2i=2.f*w1.x*w1.y;
        float w3r=w2r*w1.x-w2i*w1.y,  w3i=w2r*w1.y+w2i*w1.x;
        float y0r=t0r+t2r, y0i=t0i+t2i;
        float a1r=t1r+t3r, a1i=t1i+t3i;
        float y1r=a1r*w1.x-a1i*w1.y, y1i=a1r*w1.y+a1i*w1.x;
        float a2r=t0r-t2r, a2i=t0i-t2i;
        float y2r=a2r*w2r-a2i*w2i, y2i=a2r*w2i+a2i*w2r;
        float a3r=t1r-t3r, a3i=t1i-t3i;
        float y3r=a3r*w3r-a3i*w3i, y3i=a3r*w3i+a3i*w3r;
        Qlo[4*q]   = make_float2(y0r,y0i);
        Qlo[4*q+1] = make_float2(y1r,y1i);
        Qlo[4*q+2] = make_float2(y2r,y2i);
        Qlo[4*q+3] = make_float2(y3r,y3i);
    } else {
        const float scl = sc[0];
        int tt = t - 256;
        float ee[4], gg[4];
#pragma unroll
        for (int j = 0; j < 4; ++j) {
            int m = 4*tt + j;
            ee[j] = 0.f; gg[j] = 0.f;
            if (m < NMASK) {
                int f = m + KMIN;
                float2 Xf = B2[f], Xg = B2[2048-f];   // f=1024 -> both B2[1024]
                float hre = Xf.x + Xg.x, him = Xf.y - Xg.y;
                float sre = Xf.y + Xg.y, sim = Xg.x - Xf.x;
                float hm = scl * sqrtf(hre*hre + him*him) * MSC;
                float sm = sqrtf(sre*sre + sim*sim) * MSC;
                ee[j] = 4.f*hm*hm; gg[j] = 4.f*hm*sm;
            }
        }
        se0=ee[0]; se1=se0+ee[1]; se2=se1+ee[2]; se3=se2+ee[3];
        sg0=gg[0]; sg1=sg0+gg[1]; sg2=sg1+gg[2]; sg3=sg2+gg[3];
        totE=se3; totG=sg3; incE=totE; incG=totG;
#pragma unroll
        for (int d = 1; d < 64; d <<= 1) {
            float yE=__shfl_up(incE,d), yG=__shfl_up(incG,d);
            if (lane >= d) { incE+=yE; incG+=yG; }
        }
        if (lane == 63) { wsA[wave-4]=incE; wsB[wave-4]=incG; }
    }
    __syncthreads();                                   // B5

    // ---- I5: FFT2 r8 s=4 (t<128) || scan writeback (t>=256) ----------------
    if (t < 128) {
        fft_r8(Qlo, Qhi, 4, 128, 2, true);
    } else if (t >= 256) {
        int tt = t - 256, w4 = wave - 4;
        float offE=0.f, offG=0.f;
        for (int w = 0; w < w4; ++w) { offE+=wsA[w]; offG+=wsB[w]; }
        float preE = offE + incE - totE;
        float preG = offG + incG - totG;
        ((float4*)siA)[tt]  = make_float4(preE+se0, preE+se1, preE+se2, preE+se3);
        ((float4*)siBr)[tt] = make_float4(preG+sg0, preG+sg1, preG+sg2, preG+sg3);
    }
    __syncthreads();                                   // B6

    // ---- I6: FFT2 r8 s=32 (t<128) || w4: searchsorted+summ+chisq -----------
    if (t < 128) {
        fft_r8(Qhi, Qlo, 32, 128, 2, true);
    } else if (wave == 4) {
        float total = siA[NMASK-1];
        float qf = 1.0f / sqrtf(total);
        float total2 = siBr[NMASK-1] * qf;
        int lo = NMASK - 1;
        if (lane < 17) {
            float bin = ((float)lane * (1.0f/16.0f)) * total;
            int l0 = 0, hi = NMASK;
            while (l0 < hi) { int mid=(l0+hi)>>1; if (siA[mid] <= bin) l0=mid+1; else hi=mid; }
            lo = (l0 < NMASK-1) ? l0 : (NMASK-1);
        }
        int lon = __shfl_down(lo, 1);
        float sv = 0.f;
        if (lane < 16) {
            float snr = (siBr[lon] - siBr[lo]) * qf;
            float d = snr - total2 * (1.0f/16.0f);
            sv = d * d;
        }
        sv += __shfl_down(sv, 8);
        sv += __shfl_down(sv, 4);
        sv += __shfl_down(sv, 2);
        sv += __shfl_down(sv, 1);
        if (lane == 0) {
            float chisq = 16.0f * sv / 15.0f;
            float c3 = chisq * chisq * chisq;
            sc[7] = __powf(1.0f + c3, 1.0f/6.0f);
        }
    }
    __syncthreads();                                   // B7
    // FFT2 s=32 output in Qlo; final r4 s=256 (twiddle-free) fused below.

    // ---- I7: wave 0: fused final butterfly + Pearson (2 lags/lane) + out ---
    if (wave == 0) {
        const float scl = sc[0], Cc = sc[1], mean = sc[2];
        const float Sa = sc[3], Qa = sc[4], Szz = sc[5];
        float m = -2.0f;
#pragma unroll
        for (int rep = 0; rep < 2; ++rep) {
            int c = lane + 64 * rep;
            if (c < NWIN) {
                int off = c - MS;
                int sidx = (off >= 0) ? off : (2048 + off);
                int n = sidx >> 1;
                int q = n & 255;
                float2 x0 = Qlo[q], x1 = Qlo[q+256], x2 = Qlo[q+512], x3 = Qlo[q+768];
                float2 Fv;
                if (n < 256) {       // j = 0: y0 = (x0+x2)+(x1+x3)
                    Fv = make_float2((x0.x+x2.x)+(x1.x+x3.x), (x0.y+x2.y)+(x1.y+x3.y));
                } else {             // j = 3: y3 = t1 - t3
                    float t1r_ = x0.x - x2.x, t1i_ = x0.y - x2.y;
                    float d3r_ = x1.x - x3.x, d3i_ = x1.y - x3.y;
                    Fv = make_float2(t1r_ - d3i_, t1i_ + d3r_);
                }
                float val = (sidx & 1) ? -Fv.y : Fv.x;
                float circ = val * (1.0f/8192.0f);
                float acc = accv[c];
                float Sin_a, Sin_q, Zex, nin;
                if (off >= 0) {
                    Sin_a = Sa - Ah[off]; Sin_q = Qa - Aqh[off];
                    Zex = Xt[off] - (float)off * mean; nin = 2048.0f - (float)off;
                } else {
                    int o = -off;
                    Sin_a = Sa - At[o]; Sin_q = Qa - Aqt[o];
                    Zex = Xh[o] - (float)o * mean; nin = 2048.0f - (float)o;
                }
                float num = scl * (circ - acc) + Cc * Zex;
                float Sw  = scl * Sin_a - Cc * nin;
                float Sw2 = scl*scl*Sin_q - 2.f*scl*Cc*Sin_a + Cc*Cc*nin;
                float varw = Sw2 - Sw * Sw * (1.0f/2048.0f);
                m = fmaxf(m, num / sqrtf(varw * Szz));
            }
        }
#pragma unroll
        for (int d = 32; d; d >>= 1) m = fmaxf(m, __shfl_down(m, d));
        if (lane == 0) {
            float loss0 = (1.0f - m) / (1.0f + m);
            out[r] = loss0 * sc[7];
        }
    }
}

// ------------------------------------------------------------------
extern "C" void kernel_launch(void* const* d_in, const int* in_sizes, int n_in,
                              void* d_out, int out_size, void* d_ws, size_t ws_size,
                              hipStream_t stream) {
    const float* xhat = (const float*)d_in[0];
    const float* x    = (const float*)d_in[1];
    float* out = (float*)d_out;
    (void)in_sizes; (void)n_in; (void)out_size; (void)d_ws; (void)ws_size;

    fused_mfl_kernel<<<ROWS, 512, 0, stream>>>(xhat, x, out);
}